// Round 6
// baseline (120.397 us; speedup 1.0000x reference)
//
#include <hip/hip_runtime.h>

constexpr int Bn = 1024;
constexpr int Mn = 128;   // gt points (= pred points) per batch

// Single fused kernel. interp[m,t] = a + (t/10)*e with a=gt[m-1], e=gt[m]-gt[m-1];
// dist is quadratic in t -> evaluate the discrete vertex only. Segment constants are
// DERIVED per-iteration from a rolling previous-gt register, so the hot loop reads
// just one float4 {gt.x,gt.y,ini.x,ini.y} per iter (2-way LDS broadcast = free).
// Argmin key: (bits(d) & ~0x7F) | idx (d>=0 -> monotone bits; ties -> lower idx).
// Cross-block reduce: atomicAdd partials + counter; last block finalizes in-kernel.

__global__ __launch_bounds__(256) void dm_all(
    const float2* __restrict__ ini,    // [B,M]
    const float2* __restrict__ pred,   // [B,M]
    const float2* __restrict__ gt,     // [B,M]
    const float*  __restrict__ kpm,    // [B,M]
    float* __restrict__ acc,           // [4]: sumA, sumC, sumM, (unsigned)count
    float* __restrict__ out)           // [1]
{
    __shared__ float4 s_pts[Mn];       // gt.x, gt.y, ini.x, ini.y
    __shared__ float  s_red[3][4];

    const int b   = blockIdx.x;
    const int tid = threadIdx.x;
    const int p   = tid >> 1;          // point 0..127
    const int q   = tid & 1;           // half of the segment scan

    if (tid < Mn) {
        const float2 gv = gt [b*Mn + tid];
        const float2 iv = ini[b*Mn + tid];
        s_pts[tid] = make_float4(gv.x, gv.y, iv.x, iv.y);
    }
    __syncthreads();

    const float4 me = s_pts[p];        // broadcast (adjacent lanes share p)
    const float Px = me.z, Py = me.w;  // ini_p   (phase-A query)
    const float gx = me.x, gy = me.y;  // gt_p    (phase-B query)

    const int m0 = q * 64;
    float ax, ay;                      // rolling a = gt[m-1]
    { const float4 t0 = s_pts[(m0 + Mn - 1) & (Mn - 1)]; ax = t0.x; ay = t0.y; }

    unsigned bestA = 0xFFFFFFFFu, bestB = 0xFFFFFFFFu;
    #pragma unroll 8
    for (int i = 0; i < 64; ++i) {
        const int m = m0 + i;
        const float4 c = s_pts[m];                      // 2-way broadcast ds_read_b128
        const float ex = c.x - ax, ey = c.y - ay;       // e = gt[m] - gt[m-1]
        const float ee = fmaxf(fmaf(ex, ex, ey*ey), 1e-30f);
        const float nr = -10.0f * __builtin_amdgcn_rcpf(ee);
        // phase A: nearest interpolated gt point for pred point p
        const float fx = ax - Px, fy = ay - Py;
        const float fe = fmaf(fx, ex, fy*ey);
        const float ff = fmaf(fx, fx, fy*fy);
        const float sp = 0.1f * __builtin_amdgcn_fmed3f(rintf(fe*nr), 0.f, 9.f);
        const float d  = fmaxf(fmaf(sp, fmaf(sp, ee, fe + fe), ff), 0.f);
        bestA = min(bestA, (__float_as_uint(d) & 0xFFFFFF80u) | (unsigned)m);
        // phase B: nearest ini anchor for gt point p
        const float dx = c.z - gx, dy = c.w - gy;
        const float d2 = fmaf(dx, dx, dy*dy);
        bestB = min(bestB, (__float_as_uint(d2) & 0xFFFFFF80u) | (unsigned)m);
        ax = c.x; ay = c.y;                             // rotate
    }
    bestA = min(bestA, (unsigned)__shfl_xor((int)bestA, 1));
    bestB = min(bestB, (unsigned)__shfl_xor((int)bestB, 1));

    float sum_p2g = 0.f, sum_g2p = 0.f, sum_m = 0.f;
    if (q == 0) {
        // reconstruct nearest interp point for segment bm (one-time, divergent LDS)
        const int bm = bestA & 127;
        const float4 cb = s_pts[bm];
        const float4 cp = s_pts[(bm + Mn - 1) & (Mn - 1)];
        const float ex = cb.x - cp.x, ey = cb.y - cp.y;
        const float ee = fmaxf(fmaf(ex, ex, ey*ey), 1e-30f);
        const float nr = -10.0f * __builtin_amdgcn_rcpf(ee);
        const float fx = cp.x - Px, fy = cp.y - Py;
        const float fe = fmaf(fx, ex, fy*ey);
        const float sp = 0.1f * __builtin_amdgcn_fmed3f(rintf(fe*nr), 0.f, 9.f);
        const float ngx = fmaf(sp, ex, cp.x);
        const float ngy = fmaf(sp, ey, cp.y);
        const float2 pr = pred[b*Mn + p];
        sum_p2g = fabsf(pr.x - ngx) + fabsf(pr.y - ngy);

        const int   ni_ = bestB & 127;
        const float2 np_ = pred[b*Mn + ni_];
        const float  w   = kpm[b*Mn + p];
        sum_g2p = w * (fabsf(np_.x - gx) + fabsf(np_.y - gy));
        sum_m   = 2.0f * w;
    }

    // ---- block reduction: 3 scalars over 4 waves ----
    #pragma unroll
    for (int off = 32; off > 0; off >>= 1) {
        sum_p2g += __shfl_down(sum_p2g, off);
        sum_g2p += __shfl_down(sum_g2p, off);
        sum_m   += __shfl_down(sum_m,   off);
    }
    const int wv = tid >> 6;
    if ((tid & 63) == 0) { s_red[0][wv] = sum_p2g; s_red[1][wv] = sum_g2p; s_red[2][wv] = sum_m; }
    __syncthreads();
    if (tid == 0) {
        atomicAdd(&acc[0], s_red[0][0] + s_red[0][1] + s_red[0][2] + s_red[0][3]);
        atomicAdd(&acc[1], s_red[1][0] + s_red[1][1] + s_red[1][2] + s_red[1][3]);
        atomicAdd(&acc[2], s_red[2][0] + s_red[2][1] + s_red[2][2] + s_red[2][3]);
        __threadfence();
        const unsigned old = atomicAdd((unsigned*)&acc[3], 1u);
        if (old == (unsigned)(gridDim.x - 1)) {
            // all blocks' adds are ordered before their counter inc (fence) and
            // atomics resolve at the device coherence point -> safe to read back
            const float A = atomicAdd(&acc[0], 0.f);
            const float C = atomicAdd(&acc[1], 0.f);
            const float M = atomicAdd(&acc[2], 0.f);
            out[0] = (C / (M + 1.0f) + A * (1.0f / 262144.0f)) * 0.5f;
        }
    }
}

extern "C" void kernel_launch(void* const* d_in, const int* in_sizes, int n_in,
                              void* d_out, int out_size, void* d_ws, size_t ws_size,
                              hipStream_t stream)
{
    const float2* ini  = (const float2*)d_in[0];
    const float2* pred = (const float2*)d_in[1];
    const float2* gt   = (const float2*)d_in[2];
    const float*  kpm  = (const float*)d_in[3];
    float* out = (float*)d_out;
    float* acc = (float*)d_ws;   // 16 B: 3 float partial sums + 1 u32 counter

    hipMemsetAsync(acc, 0, 16, stream);
    dm_all<<<Bn, 256, 0, stream>>>(ini, pred, gt, kpm, acc, out);
}

// Round 7
// 73.935 us; speedup vs baseline: 1.6284x; 1.6284x over previous
//
#include <hip/hip_runtime.h>

constexpr int Bn = 1024;
constexpr int Mn = 128;   // gt points (= pred points) per batch

// interp[m,t] = a + (t/10)*e, a=gt[m-1], e=gt[m]-gt[m-1]; dist quadratic in t ->
// evaluate the discrete vertex only. Per-segment constants precomputed ONCE per
// block into LDS. 8 threads/point, thread q scans segments m=8i+q: float4 LDS
// addresses hit bank-quad 4q -> the 8 broadcast groups use 8 DISTINCT bank quads
// (conflict-free ds_read_b128). Argmin key: (bits(d) & ~0x7F) | m  (d>=0 ->
// monotone bits; ties -> lower m = np first-occurrence semantics).

__global__ __launch_bounds__(1024) void dm_main(
    const float2* __restrict__ ini,    // [B,M]
    const float2* __restrict__ pred,   // [B,M]
    const float2* __restrict__ gt,     // [B,M]
    const float*  __restrict__ kpm,    // [B,M]
    float4* __restrict__ part)         // [B]
{
    __shared__ float4 s_A[Mn];         // a.x, a.y, e.x, e.y
    __shared__ float4 s_B[Mn];         // ee, nr=-10/ee, ini.x, ini.y
    __shared__ float  s_red[3][16];

    const int b   = blockIdx.x;
    const int tid = threadIdx.x;
    const int p   = tid >> 3;          // point 0..127
    const int q   = tid & 7;           // eighth of the segment scan

    if (tid < Mn) {
        const float2 cur = gt[b*Mn + tid];
        const float2 prv = gt[b*Mn + ((tid + 127) & 127)];
        const float2 ii  = ini[b*Mn + tid];
        const float ex = cur.x - prv.x, ey = cur.y - prv.y;
        const float ee = fmaxf(fmaf(ex, ex, ey*ey), 1e-30f);
        const float nr = -10.0f * __builtin_amdgcn_rcpf(ee);
        s_A[tid] = make_float4(prv.x, prv.y, ex, ey);
        s_B[tid] = make_float4(ee, nr, ii.x, ii.y);
    }
    __syncthreads();

    // queries from LDS: ini[p] sits in s_B[p].zw; gt[p] = prv of segment p+1
    const float4 mb = s_B[p];
    const float4 ma = s_A[(p + 1) & 127];
    const float Px = mb.z, Py = mb.w;  // phase-A query (ini point p)
    const float gx = ma.x, gy = ma.y;  // phase-B query (gt point p)

    unsigned bestA = 0xFFFFFFFFu, bestB = 0xFFFFFFFFu;
    #pragma unroll
    for (int i = 0; i < 16; ++i) {
        const int m = (i << 3) | q;               // stride-8 interleave: conflict-free
        const float4 A  = s_A[m];
        const float4 Bv = s_B[m];
        // phase A: nearest interpolated gt point for pred point p
        const float fx = A.x - Px, fy = A.y - Py;
        const float fe = fmaf(fx, A.z, fy*A.w);
        const float ff = fmaf(fx, fx, fy*fy);
        const float sp = 0.1f * __builtin_amdgcn_fmed3f(rintf(fe*Bv.y), 0.f, 9.f);
        const float d  = fmaxf(fmaf(sp, fmaf(sp, Bv.x, fe + fe), ff), 0.f);
        bestA = min(bestA, (__float_as_uint(d) & 0xFFFFFF80u) | (unsigned)m);
        // phase B: nearest ini anchor for gt point p
        const float dx = Bv.z - gx, dy = Bv.w - gy;
        const float d2 = fmaf(dx, dx, dy*dy);
        bestB = min(bestB, (__float_as_uint(d2) & 0xFFFFFF80u) | (unsigned)m);
    }
    // merge the 8 sub-scans (adjacent lanes 8k..8k+7 share point p)
    bestA = min(bestA, (unsigned)__shfl_xor((int)bestA, 1));
    bestA = min(bestA, (unsigned)__shfl_xor((int)bestA, 2));
    bestA = min(bestA, (unsigned)__shfl_xor((int)bestA, 4));
    bestB = min(bestB, (unsigned)__shfl_xor((int)bestB, 1));
    bestB = min(bestB, (unsigned)__shfl_xor((int)bestB, 2));
    bestB = min(bestB, (unsigned)__shfl_xor((int)bestB, 4));

    float sum_p2g = 0.f, sum_g2p = 0.f, sum_m = 0.f;
    if (q == 0) {
        // reconstruct nearest interp point (one-time divergent LDS reads)
        const int bm = bestA & 127;
        const float4 RA = s_A[bm];
        const float4 RB = s_B[bm];
        const float fx = RA.x - Px, fy = RA.y - Py;
        const float fe = fmaf(fx, RA.z, fy*RA.w);
        const float sp = 0.1f * __builtin_amdgcn_fmed3f(rintf(fe*RB.y), 0.f, 9.f);
        const float ngx = fmaf(sp, RA.z, RA.x);
        const float ngy = fmaf(sp, RA.w, RA.y);
        const float2 pr = pred[b*Mn + p];
        sum_p2g = fabsf(pr.x - ngx) + fabsf(pr.y - ngy);

        const int   ni_ = bestB & 127;
        const float2 np_ = pred[b*Mn + ni_];
        const float  w   = kpm[b*Mn + p];
        sum_g2p = w * (fabsf(np_.x - gx) + fabsf(np_.y - gy));
        sum_m   = 2.0f * w;
    }

    // block reduction: 3 scalars over 16 waves
    #pragma unroll
    for (int off = 32; off > 0; off >>= 1) {
        sum_p2g += __shfl_down(sum_p2g, off);
        sum_g2p += __shfl_down(sum_g2p, off);
        sum_m   += __shfl_down(sum_m,   off);
    }
    const int wv = tid >> 6;
    if ((tid & 63) == 0) { s_red[0][wv] = sum_p2g; s_red[1][wv] = sum_g2p; s_red[2][wv] = sum_m; }
    __syncthreads();
    if (tid == 0) {
        float A = 0.f, C = 0.f, M = 0.f;
        #pragma unroll
        for (int i = 0; i < 16; ++i) { A += s_red[0][i]; C += s_red[1][i]; M += s_red[2][i]; }
        part[b] = make_float4(A, C, M, 0.f);
    }
}

__global__ __launch_bounds__(1024) void dm_final(const float4* __restrict__ part,
                                                 float* __restrict__ out)
{
    __shared__ float s_red[3][16];
    const int tid = threadIdx.x;
    const float4 v = part[tid];
    float a = v.x, c = v.y, m = v.z;
    #pragma unroll
    for (int off = 32; off > 0; off >>= 1) {
        a += __shfl_down(a, off); c += __shfl_down(c, off); m += __shfl_down(m, off);
    }
    const int wv = tid >> 6;
    if ((tid & 63) == 0) { s_red[0][wv] = a; s_red[1][wv] = c; s_red[2][wv] = m; }
    __syncthreads();
    if (tid == 0) {
        float A = 0.f, C = 0.f, M = 0.f;
        #pragma unroll
        for (int i = 0; i < 16; ++i) { A += s_red[0][i]; C += s_red[1][i]; M += s_red[2][i]; }
        out[0] = (C / (M + 1.0f) + A * (1.0f / 262144.0f)) * 0.5f;
    }
}

extern "C" void kernel_launch(void* const* d_in, const int* in_sizes, int n_in,
                              void* d_out, int out_size, void* d_ws, size_t ws_size,
                              hipStream_t stream)
{
    const float2* ini  = (const float2*)d_in[0];
    const float2* pred = (const float2*)d_in[1];
    const float2* gt   = (const float2*)d_in[2];
    const float*  kpm  = (const float*)d_in[3];
    float*  out  = (float*)d_out;
    float4* part = (float4*)d_ws;   // 16 KiB, fully rewritten every call

    dm_main <<<Bn, 1024, 0, stream>>>(ini, pred, gt, kpm, part);
    dm_final<<<1, 1024, 0, stream>>>(part, out);
}